// Round 7
// baseline (264.871 us; speedup 1.0000x reference)
//
#include <hip/hip_runtime.h>

#define NN   32768
#define HD   128
#define EE   524288
#define GG   256
#define EPG  2048
#define CCd  16
#define LLd  3
#define SSTR 136   // LDS row stride in shorts

typedef short short8 __attribute__((ext_vector_type(8)));   // 8 bf16 = 4 VGPRs
typedef float f32x4 __attribute__((ext_vector_type(4)));

__device__ __forceinline__ unsigned short f2bf(float f) {
  unsigned u = __builtin_bit_cast(unsigned, f);
  return (unsigned short)((u + 0x7FFFu + ((u >> 16) & 1u)) >> 16);  // RNE
}
__device__ __forceinline__ unsigned bfpack(float a, float b) {
  return (unsigned)f2bf(a) | ((unsigned)f2bf(b) << 16);
}
#define MFMA __builtin_amdgcn_mfma_f32_16x16x32_bf16

// ---------------- prep: blocks [0,256) per-graph M~ ; blocks [256,304) weight convert ----------------
__global__ __launch_bounds__(256) void prep_kernel(const int* __restrict__ src, const int* __restrict__ tgt,
                                                   const int* __restrict__ mask,
                                                   const float* __restrict__ Wn, const float* __restrict__ Wo,
                                                   const float* __restrict__ Wr, const float* __restrict__ bo,
                                                   unsigned* __restrict__ Mb, float* __restrict__ fin,
                                                   float* __restrict__ fout,
                                                   unsigned* __restrict__ Wnb, unsigned* __restrict__ Wob,
                                                   unsigned* __restrict__ Wrb, float* __restrict__ wsreg) {
  __shared__ unsigned Mi[2 * 128 * 64];   // 64 KB packed u16 counts [dir][t][s/2]
  const int tid = threadIdx.x;
  if (blockIdx.x >= GG) {                 // ---- weight-convert path ----
    int i = (blockIdx.x - GG) * 256 + tid;
    float4 a = *(const float4*)(Wn + (size_t)i * 4);
    float4 b = *(const float4*)(Wo + (size_t)i * 4);
    float4 c = *(const float4*)(Wr + (size_t)i * 4);
    *(uint2*)(Wnb + (size_t)i * 2) = make_uint2(bfpack(a.x, a.y), bfpack(a.z, a.w));
    *(uint2*)(Wob + (size_t)i * 2) = make_uint2(bfpack(b.x, b.y), bfpack(b.z, b.w));
    *(uint2*)(Wrb + (size_t)i * 2) = make_uint2(bfpack(c.x, c.y), bfpack(c.z, c.w));
    float s = fabsf(b.x) + fabsf(b.y) + fabsf(b.z) + fabsf(b.w);
    if (blockIdx.x == GG && tid < 96) {
      float4 d = *(const float4*)(bo + tid * 4);
      s += fabsf(d.x) + fabsf(d.y) + fabsf(d.z) + fabsf(d.w);
    }
#pragma unroll
    for (int mk = 1; mk < 64; mk <<= 1) s += __shfl_xor(s, mk, 64);
    if ((tid & 63) == 0) atomicAdd(wsreg, s);
    return;
  }
  // ---- adjacency path ----
  const int g = blockIdx.x;
  uint4* Mi4 = (uint4*)Mi;
  for (int i = tid; i < 4096; i += 256) Mi4[i] = make_uint4(0, 0, 0, 0);
  __syncthreads();
  const int e0 = g * EPG;
#pragma unroll
  for (int i = 0; i < 8; ++i) {
    int e = e0 + i * 256 + tid;
    int t = tgt[e] & 127;
    int sl = src[e] & 127;
    int dir = (mask[e] != 0) ? 0 : 1;
    atomicAdd(&Mi[dir * 8192 + t * 64 + (sl >> 1)], 1u << ((sl & 1) * 16));
  }
  __syncthreads();
  const int t = tid >> 1, p = tid & 1;
  const int b0 = t * 64 + p * 32;
  unsigned nin = 0, nout = 0;
#pragma unroll 8
  for (int k = 0; k < 32; ++k) { unsigned v = Mi[b0 + ((k + t) & 31)]; nin += (v & 0xffffu) + (v >> 16); }
#pragma unroll 8
  for (int k = 0; k < 32; ++k) { unsigned v = Mi[8192 + b0 + ((k + t) & 31)]; nout += (v & 0xffffu) + (v >> 16); }
  nin += __shfl_xor((int)nin, 1);
  nout += __shfl_xor((int)nout, 1);
  unsigned dg = nin + nout;
  float inv = 1.0f / (float)(dg > 0 ? dg : 1);
  if (p == 0) { fin[g * 128 + t] = (float)nin * inv; fout[g * 128 + t] = (float)nout * inv; }
#pragma unroll
  for (int dir = 0; dir < 2; ++dir) {
    int base = dir * 8192 + b0;
#pragma unroll 8
    for (int k = 0; k < 32; ++k) {
      int kk = (k + t) & 31;
      unsigned v = Mi[base + kk];
      Mb[(size_t)g * 16384 + base + kk] = bfpack((float)(v & 0xffffu) * inv, (float)(v >> 16) * inv);
    }
  }
}

// ---------------- head: x -> bf16 h0 ; Yt0 = (h0·Wn0^T)^T, Zt0 = (h0·Wo0^T)^T ----------------
// grid 512 (2 blocks/graph, 64 rows each), 256 threads (4 waves x 16 rows).
__global__ __launch_bounds__(256, 4) void head_kernel(
    const float* __restrict__ x,
    const unsigned short* __restrict__ Wn0, const unsigned short* __restrict__ Wo0,
    unsigned short* __restrict__ hOut, unsigned short* __restrict__ YtO, unsigned short* __restrict__ ZtO) {
  __shared__ unsigned short hloc[64 * SSTR];  // 17.4 KB
  const int g = blockIdx.x >> 1, half = blockIdx.x & 1;
  const int tid = threadIdx.x;
  const int wave = tid >> 6, lane = tid & 63;
  const int m = lane & 15, q = lane >> 4;
  unsigned* hloc32 = (unsigned*)hloc;
  const float4* xg = (const float4*)(x + (size_t)g * 16384 + (size_t)half * 8192);
#pragma unroll
  for (int i = 0; i < 8; ++i) {
    int flat = i * 256 + tid;          // 2048 float4s = 64 rows x 32
    int t = flat >> 5, f = (flat & 31) << 2;
    float4 v = xg[flat];
    int w0 = (t * SSTR + f) >> 1;
    hloc32[w0] = bfpack(v.x, v.y);
    hloc32[w0 + 1] = bfpack(v.z, v.w);
  }
  __syncthreads();
#pragma unroll
  for (int i = 0; i < 4; ++i) {        // h0 coalesced global write
    int flat = i * 256 + tid;          // 1024 uint4
    int t = flat >> 4, f = (flat & 15) << 3;
    *(uint4*)(hOut + (size_t)g * 16384 + (size_t)(half * 64 + t) * 128 + f) =
        *(const uint4*)&hloc[t * SSTR + f];
  }
  short8 afr[4];
#pragma unroll
  for (int ks = 0; ks < 4; ++ks)
    afr[ks] = *(const short8*)&hloc[(wave * 16 + m) * SSTR + ks * 32 + q * 8];
  const int srow = half * 64 + wave * 16 + q * 4;
#pragma unroll
  for (int ct = 0; ct < 8; ++ct) {
    f32x4 y = (f32x4){0.f, 0.f, 0.f, 0.f}, z = (f32x4){0.f, 0.f, 0.f, 0.f};
#pragma unroll
    for (int ks = 0; ks < 4; ++ks) {
      short8 bnn = *(const short8*)(Wn0 + (size_t)(ct * 16 + m) * 128 + ks * 32 + q * 8);
      short8 boo = *(const short8*)(Wo0 + (size_t)(ct * 16 + m) * 128 + ks * 32 + q * 8);
      y = MFMA(afr[ks], bnn, y, 0, 0, 0);
      z = MFMA(afr[ks], boo, z, 0, 0, 0);
    }
    size_t o = (size_t)g * 16384 + (size_t)(ct * 16 + m) * 128 + srow;
    *(uint2*)(YtO + o) = make_uint2(bfpack(y[0], y[1]), bfpack(y[2], y[3]));
    *(uint2*)(ZtO + o) = make_uint2(bfpack(z[0], z[1]), bfpack(z[2], z[3]));
  }
}

// ---------------- mid layer: pre = M~in·Y + M~out·Z + h·Wr^T ; LN+ReLU -> h' ; Yt'/Zt' ----------------
// grid 512 (2 blocks/graph), 256 threads. Phase 1 operands are all global/L2 (no LDS, no barriers).
__global__ __launch_bounds__(256, 4) void mid_kernel(
    const unsigned short* __restrict__ Mb,
    const unsigned short* __restrict__ Yt, const unsigned short* __restrict__ Zt,
    const unsigned short* __restrict__ hIn, const unsigned short* __restrict__ Wr,
    const float* __restrict__ bn, const float* __restrict__ bo,
    const float* __restrict__ fin, const float* __restrict__ fout,
    const float* __restrict__ lng, const float* __restrict__ lnb,
    const unsigned short* __restrict__ WnN, const unsigned short* __restrict__ WoN,
    unsigned short* __restrict__ hOut, unsigned short* __restrict__ YtO, unsigned short* __restrict__ ZtO) {
  __shared__ unsigned short hloc[64 * SSTR];  // 17.4 KB
  const int g = blockIdx.x >> 1, half = blockIdx.x & 1;
  const int tid = threadIdx.x;
  const int wave = tid >> 6, lane = tid & 63;
  const int m = lane & 15, q = lane >> 4;
  const int trow = half * 64 + wave * 16;
  const unsigned short* Mg = Mb + (size_t)g * 32768;
  const unsigned short* Ytg = Yt + (size_t)g * 16384;
  const unsigned short* Ztg = Zt + (size_t)g * 16384;
  const unsigned short* hg = hIn + (size_t)g * 16384;

  f32x4 pre[8];
#pragma unroll
  for (int ct = 0; ct < 8; ++ct) pre[ct] = (f32x4){0.f, 0.f, 0.f, 0.f};
  // aggregation via dense M~ (A = M~ rows, B = Yt/Zt rows; all contiguous 16B global)
#pragma unroll
  for (int sc = 0; sc < 4; ++sc) {
    short8 am0 = *(const short8*)(Mg + (size_t)(trow + m) * 128 + sc * 32 + q * 8);
    short8 am1 = *(const short8*)(Mg + 16384 + (size_t)(trow + m) * 128 + sc * 32 + q * 8);
#pragma unroll
    for (int ct = 0; ct < 8; ++ct) {
      short8 b0 = *(const short8*)(Ytg + (size_t)(ct * 16 + m) * 128 + sc * 32 + q * 8);
      short8 b1 = *(const short8*)(Ztg + (size_t)(ct * 16 + m) * 128 + sc * 32 + q * 8);
      pre[ct] = MFMA(am0, b0, pre[ct], 0, 0, 0);
      pre[ct] = MFMA(am1, b1, pre[ct], 0, 0, 0);
    }
  }
  // + h·Wr^T
#pragma unroll
  for (int ks = 0; ks < 4; ++ks) {
    short8 a = *(const short8*)(hg + (size_t)(trow + m) * 128 + ks * 32 + q * 8);
#pragma unroll
    for (int ct = 0; ct < 8; ++ct) {
      short8 b = *(const short8*)(Wr + (size_t)(ct * 16 + m) * 128 + ks * 32 + q * 8);
      pre[ct] = MFMA(a, b, pre[ct], 0, 0, 0);
    }
  }
  // epilogue: bias mix + LN + ReLU -> hloc
  float bnv[8], bov[8], gv[8], bv[8];
#pragma unroll
  for (int ct = 0; ct < 8; ++ct) {
    int c = ct * 16 + m;
    bnv[ct] = bn[c]; bov[ct] = bo[c]; gv[ct] = lng[c]; bv[ct] = lnb[c];
  }
#pragma unroll
  for (int r = 0; r < 4; ++r) {
    const int T = g * 128 + trow + q * 4 + r;
    const float fiv = fin[T], fov = fout[T];
    float v[8];
    float sum = 0.f;
#pragma unroll
    for (int ct = 0; ct < 8; ++ct) {
      v[ct] = pre[ct][r] + fiv * bnv[ct] + fov * bov[ct];
      sum += v[ct];
    }
    sum += __shfl_xor(sum, 1); sum += __shfl_xor(sum, 2);
    sum += __shfl_xor(sum, 4); sum += __shfl_xor(sum, 8);
    const float mu = sum * (1.0f / 128.0f);
    float sq = 0.f;
#pragma unroll
    for (int ct = 0; ct < 8; ++ct) { float d = v[ct] - mu; sq += d * d; }
    sq += __shfl_xor(sq, 1); sq += __shfl_xor(sq, 2);
    sq += __shfl_xor(sq, 4); sq += __shfl_xor(sq, 8);
    const float rstd = rsqrtf(sq * (1.0f / 128.0f) + 1e-5f);
#pragma unroll
    for (int ct = 0; ct < 8; ++ct) {
      float o = fmaxf((v[ct] - mu) * rstd * gv[ct] + bv[ct], 0.0f);
      hloc[(wave * 16 + q * 4 + r) * SSTR + ct * 16 + m] = f2bf(o);
    }
  }
  __syncthreads();
#pragma unroll
  for (int i = 0; i < 4; ++i) {        // h' coalesced global write
    int flat = i * 256 + tid;
    int t = flat >> 4, f = (flat & 15) << 3;
    *(uint4*)(hOut + (size_t)g * 16384 + (size_t)(half * 64 + t) * 128 + f) =
        *(const uint4*)&hloc[t * SSTR + f];
  }
  // phase 2: Yt'/Zt' for next layer
  short8 afr[4];
#pragma unroll
  for (int ks = 0; ks < 4; ++ks)
    afr[ks] = *(const short8*)&hloc[(wave * 16 + m) * SSTR + ks * 32 + q * 8];
  const int srow = half * 64 + wave * 16 + q * 4;
#pragma unroll
  for (int ct = 0; ct < 8; ++ct) {
    f32x4 y = (f32x4){0.f, 0.f, 0.f, 0.f}, z = (f32x4){0.f, 0.f, 0.f, 0.f};
#pragma unroll
    for (int ks = 0; ks < 4; ++ks) {
      short8 bnn = *(const short8*)(WnN + (size_t)(ct * 16 + m) * 128 + ks * 32 + q * 8);
      short8 boo = *(const short8*)(WoN + (size_t)(ct * 16 + m) * 128 + ks * 32 + q * 8);
      y = MFMA(afr[ks], bnn, y, 0, 0, 0);
      z = MFMA(afr[ks], boo, z, 0, 0, 0);
    }
    size_t o = (size_t)g * 16384 + (size_t)(ct * 16 + m) * 128 + srow;
    *(uint2*)(YtO + o) = make_uint2(bfpack(y[0], y[1]), bfpack(y[2], y[3]));
    *(uint2*)(ZtO + o) = make_uint2(bfpack(z[0], z[1]), bfpack(z[2], z[3]));
  }
}

// ---------------- tail: layer-2 phase1 + LN ; pool ; final LN + lin + mask ----------------
// grid 256 (1 block/graph), 512 threads (8 waves x 16 rows).
__global__ __launch_bounds__(512, 2) void tail_kernel(
    const unsigned short* __restrict__ Mb,
    const unsigned short* __restrict__ Yt, const unsigned short* __restrict__ Zt,
    const unsigned short* __restrict__ hIn, const unsigned short* __restrict__ Wr,
    const float* __restrict__ bn, const float* __restrict__ bo,
    const float* __restrict__ fin, const float* __restrict__ fout,
    const float* __restrict__ lng, const float* __restrict__ lnb,
    const float* __restrict__ s,
    const float* __restrict__ flng, const float* __restrict__ flnb,
    const float* __restrict__ linw, const float* __restrict__ bias,
    float* __restrict__ out, float* __restrict__ l1g) {
  __shared__ unsigned short hloc[128 * SSTR];  // 34.8 KB
  __shared__ unsigned short sTs[16 * SSTR];    //  4.3 KB
  __shared__ float pooledS[16 * 132];          //  8.4 KB
  __shared__ float colsumS[CCd], xcs[CCd], axcs[CCd], msk[CCd];
  const int g = blockIdx.x;
  const int tid = threadIdx.x;
  const int wave = tid >> 6, lane = tid & 63;
  const int m = lane & 15, q = lane >> 4;
  const int trow = wave * 16;
  const unsigned short* Mg = Mb + (size_t)g * 32768;
  const unsigned short* Ytg = Yt + (size_t)g * 16384;
  const unsigned short* Ztg = Zt + (size_t)g * 16384;
  const unsigned short* hg = hIn + (size_t)g * 16384;

  {  // sT staging + colsum
    int t = tid >> 2, c0 = (tid & 3) << 2;
    float4 v = *(const float4*)(s + (size_t)g * 2048 + t * 16 + c0);
    sTs[(c0 + 0) * SSTR + t] = f2bf(v.x);
    sTs[(c0 + 1) * SSTR + t] = f2bf(v.y);
    sTs[(c0 + 2) * SSTR + t] = f2bf(v.z);
    sTs[(c0 + 3) * SSTR + t] = f2bf(v.w);
    if (tid < CCd) {
      float cs = 0.f;
      for (int tt = 0; tt < 128; ++tt) cs += s[(size_t)g * 2048 + tt * 16 + tid];
      colsumS[tid] = cs;
    }
  }

  f32x4 pre[8];
#pragma unroll
  for (int ct = 0; ct < 8; ++ct) pre[ct] = (f32x4){0.f, 0.f, 0.f, 0.f};
#pragma unroll
  for (int sc = 0; sc < 4; ++sc) {
    short8 am0 = *(const short8*)(Mg + (size_t)(trow + m) * 128 + sc * 32 + q * 8);
    short8 am1 = *(const short8*)(Mg + 16384 + (size_t)(trow + m) * 128 + sc * 32 + q * 8);
#pragma unroll
    for (int ct = 0; ct < 8; ++ct) {
      short8 b0 = *(const short8*)(Ytg + (size_t)(ct * 16 + m) * 128 + sc * 32 + q * 8);
      short8 b1 = *(const short8*)(Ztg + (size_t)(ct * 16 + m) * 128 + sc * 32 + q * 8);
      pre[ct] = MFMA(am0, b0, pre[ct], 0, 0, 0);
      pre[ct] = MFMA(am1, b1, pre[ct], 0, 0, 0);
    }
  }
#pragma unroll
  for (int ks = 0; ks < 4; ++ks) {
    short8 a = *(const short8*)(hg + (size_t)(trow + m) * 128 + ks * 32 + q * 8);
#pragma unroll
    for (int ct = 0; ct < 8; ++ct) {
      short8 b = *(const short8*)(Wr + (size_t)(ct * 16 + m) * 128 + ks * 32 + q * 8);
      pre[ct] = MFMA(a, b, pre[ct], 0, 0, 0);
    }
  }
  float bnv[8], bov[8], gv[8], bv[8];
#pragma unroll
  for (int ct = 0; ct < 8; ++ct) {
    int c = ct * 16 + m;
    bnv[ct] = bn[c]; bov[ct] = bo[c]; gv[ct] = lng[c]; bv[ct] = lnb[c];
  }
#pragma unroll
  for (int r = 0; r < 4; ++r) {
    const int T = g * 128 + trow + q * 4 + r;
    const float fiv = fin[T], fov = fout[T];
    float v[8];
    float sum = 0.f;
#pragma unroll
    for (int ct = 0; ct < 8; ++ct) {
      v[ct] = pre[ct][r] + fiv * bnv[ct] + fov * bov[ct];
      sum += v[ct];
    }
    sum += __shfl_xor(sum, 1); sum += __shfl_xor(sum, 2);
    sum += __shfl_xor(sum, 4); sum += __shfl_xor(sum, 8);
    const float mu = sum * (1.0f / 128.0f);
    float sq = 0.f;
#pragma unroll
    for (int ct = 0; ct < 8; ++ct) { float d = v[ct] - mu; sq += d * d; }
    sq += __shfl_xor(sq, 1); sq += __shfl_xor(sq, 2);
    sq += __shfl_xor(sq, 4); sq += __shfl_xor(sq, 8);
    const float rstd = rsqrtf(sq * (1.0f / 128.0f) + 1e-5f);
#pragma unroll
    for (int ct = 0; ct < 8; ++ct) {
      float o = fmaxf((v[ct] - mu) * rstd * gv[ct] + bv[ct], 0.0f);
      hloc[(trow + q * 4 + r) * SSTR + ct * 16 + m] = f2bf(o);
    }
  }
  __syncthreads();
  // pool: wave w computes fo-tile w
  {
    f32x4 pl = (f32x4){0.f, 0.f, 0.f, 0.f};
#pragma unroll
    for (int ks = 0; ks < 4; ++ks) {
      short8 a = *(const short8*)&sTs[m * SSTR + ks * 32 + q * 8];
      short8 b;
#pragma unroll
      for (int j = 0; j < 8; ++j)
        b[j] = (short)hloc[(ks * 32 + q * 8 + j) * SSTR + wave * 16 + m];
      pl = MFMA(a, b, pl, 0, 0, 0);
    }
#pragma unroll
    for (int r = 0; r < 4; ++r) pooledS[(q * 4 + r) * 132 + wave * 16 + m] = pl[r];
  }
  __syncthreads();
  if (tid < 256) {
    const int c = tid >> 4;
    const int j0 = (tid & 15) << 3;
    float v[8];
#pragma unroll
    for (int jj = 0; jj < 8; ++jj) v[jj] = pooledS[c * 132 + j0 + jj];
    float sum = 0.f;
#pragma unroll
    for (int jj = 0; jj < 8; ++jj) sum += v[jj];
#pragma unroll
    for (int mk = 1; mk < 16; mk <<= 1) sum += __shfl_xor(sum, mk, 64);
    float mu = sum * (1.0f / 128.0f);
    float sq = 0.f;
#pragma unroll
    for (int jj = 0; jj < 8; ++jj) { float d = v[jj] - mu; sq += d * d; }
#pragma unroll
    for (int mk = 1; mk < 16; mk <<= 1) sq += __shfl_xor(sq, mk, 64);
    float rstd = rsqrtf(sq * (1.0f / 128.0f) + 1e-5f);
    float dot = 0.f;
#pragma unroll
    for (int jj = 0; jj < 8; ++jj) {
      float nv = (v[jj] - mu) * rstd * flng[j0 + jj] + flnb[j0 + jj];
      dot += nv * linw[j0 + jj];
    }
#pragma unroll
    for (int mk = 1; mk < 16; mk <<= 1) dot += __shfl_xor(dot, mk, 64);
    if ((tid & 15) == 0) {
      float cm = (colsumS[c] > 0.f) ? 1.0f : 0.0f;
      float xcv = dot * cm;
      out[257 + g * CCd + c] = xcv;
      xcs[c] = xcv; axcs[c] = fabsf(xcv); msk[c] = cm;
    }
  }
  __syncthreads();
  if (tid == 0) {
    float so = 0.f, sa = 0.f, sd = 0.f;
#pragma unroll
    for (int k = 0; k < CCd; ++k) { so += xcs[k]; sa += axcs[k]; sd += msk[k] + 1e-7f; }
    out[g] = so + bias[0];
    l1g[g] = sa / sd;
  }
}

// ---------------- combine: losses = 0.01*reg + 0.01*mean_g(l1g) ----------------
__global__ __launch_bounds__(256) void combine_kernel(const float* __restrict__ l1g, const float* __restrict__ wsreg,
                                                      float* __restrict__ outp) {
  const int tid = threadIdx.x;
  float s2 = l1g[tid];
#pragma unroll
  for (int mk = 1; mk < 64; mk <<= 1) s2 += __shfl_xor(s2, mk, 64);
  __shared__ float rs2[4];
  if ((tid & 63) == 0) rs2[tid >> 6] = s2;
  __syncthreads();
  if (tid == 0) {
    float l1 = (rs2[0] + rs2[1] + rs2[2] + rs2[3]) * (1.0f / GG);
    outp[0] = 0.01f * wsreg[0] + 0.01f * l1;
  }
}

extern "C" void kernel_launch(void* const* d_in, const int* in_sizes, int n_in,
                              void* d_out, int out_size, void* d_ws, size_t ws_size,
                              hipStream_t stream) {
  (void)in_sizes; (void)n_in; (void)out_size; (void)ws_size;
  const float* x    = (const float*)d_in[0];
  const int*   ei   = (const int*)d_in[1];
  const int*   mask = (const int*)d_in[2];
  const float* s    = (const float*)d_in[3];
  const float* Wn   = (const float*)d_in[5];
  const float* bn   = (const float*)d_in[6];
  const float* Wo   = (const float*)d_in[7];
  const float* bo   = (const float*)d_in[8];
  const float* Wr   = (const float*)d_in[9];
  const float* lng  = (const float*)d_in[10];
  const float* lnb  = (const float*)d_in[11];
  const float* flng = (const float*)d_in[12];
  const float* flnb = (const float*)d_in[13];
  const float* linw = (const float*)d_in[14];
  const float* bias = (const float*)d_in[15];
  float* out = (float*)d_out;

  char* ws = (char*)d_ws;
  size_t off = 0;
  auto alloc = [&](size_t b) { char* p = ws + off; off += (b + 255) & ~(size_t)255; return p; };
  unsigned short* Mbuf = (unsigned short*)alloc((size_t)GG * 2 * 128 * 128 * 2);  // 16.8 MB
  float* fin    = (float*)alloc((size_t)NN * 4);
  float* fout   = (float*)alloc((size_t)NN * 4);
  unsigned short* Wnb = (unsigned short*)alloc((size_t)LLd * HD * HD * 2);
  unsigned short* Wob = (unsigned short*)alloc((size_t)LLd * HD * HD * 2);
  unsigned short* Wrb = (unsigned short*)alloc((size_t)LLd * HD * HD * 2);
  unsigned short* hA  = (unsigned short*)alloc((size_t)NN * HD * 2);
  unsigned short* hB  = (unsigned short*)alloc((size_t)NN * HD * 2);
  unsigned short* YtA = (unsigned short*)alloc((size_t)NN * HD * 2);
  unsigned short* ZtA = (unsigned short*)alloc((size_t)NN * HD * 2);
  unsigned short* YtB = (unsigned short*)alloc((size_t)NN * HD * 2);
  unsigned short* ZtB = (unsigned short*)alloc((size_t)NN * HD * 2);
  float* l1g    = (float*)alloc((size_t)GG * 4);
  float* wsreg  = (float*)alloc(256);

  const int* srcA = ei;
  const int* tgtA = ei + EE;

  hipMemsetAsync(wsreg, 0, 4, stream);
  prep_kernel<<<GG + 48, 256, 0, stream>>>(srcA, tgtA, mask, Wn, Wo, Wr, bo,
      (unsigned*)Mbuf, fin, fout, (unsigned*)Wnb, (unsigned*)Wob, (unsigned*)Wrb, wsreg);
  head_kernel<<<2 * GG, 256, 0, stream>>>(x, Wnb, Wob, hA, YtA, ZtA);
  mid_kernel<<<2 * GG, 256, 0, stream>>>(Mbuf, YtA, ZtA, hA, Wrb,
      bn, bo, fin, fout, lng, lnb, Wnb + 16384, Wob + 16384, hB, YtB, ZtB);
  mid_kernel<<<2 * GG, 256, 0, stream>>>(Mbuf, YtB, ZtB, hB, Wrb + 16384,
      bn + 128, bo + 128, fin, fout, lng + 128, lnb + 128, Wnb + 32768, Wob + 32768, hA, YtA, ZtA);
  tail_kernel<<<GG, 512, 0, stream>>>(Mbuf, YtA, ZtA, hA, Wrb + 32768,
      bn + 256, bo + 256, fin, fout, lng + 256, lnb + 256, s, flng, flnb, linw, bias, out, l1g);
  combine_kernel<<<1, 256, 0, stream>>>(l1g, wsreg, out + 256);
}

// Round 9
// 196.182 us; speedup vs baseline: 1.3501x; 1.3501x over previous
//
#include <hip/hip_runtime.h>

#define NN   32768
#define HD   128
#define EE   524288
#define GG   256
#define EPG  2048
#define CCd  16
#define LLd  3
#define SSTR 136   // scratch stride in shorts
#define YSTR 44    // ys stride in shorts (32 data + 12 pad)

typedef short short8 __attribute__((ext_vector_type(8)));   // 8 bf16 = 4 VGPRs
typedef float f32x4 __attribute__((ext_vector_type(4)));

__device__ __forceinline__ unsigned short f2bf(float f) {
  unsigned u = __builtin_bit_cast(unsigned, f);
  return (unsigned short)((u + 0x7FFFu + ((u >> 16) & 1u)) >> 16);  // RNE
}
__device__ __forceinline__ unsigned bfpack(float a, float b) {
  return (unsigned)f2bf(a) | ((unsigned)f2bf(b) << 16);
}
#define MFMA __builtin_amdgcn_mfma_f32_16x16x32_bf16

// ---------------- prep: blocks [0,256) per-graph M~ ; blocks [256,304) weight convert ----------------
__global__ __launch_bounds__(256) void prep_kernel(const int* __restrict__ src, const int* __restrict__ tgt,
                                                   const int* __restrict__ mask,
                                                   const float* __restrict__ Wn, const float* __restrict__ Wo,
                                                   const float* __restrict__ Wr, const float* __restrict__ bo,
                                                   unsigned* __restrict__ Mb, float* __restrict__ fin,
                                                   float* __restrict__ fout,
                                                   unsigned* __restrict__ Wnb, unsigned* __restrict__ Wob,
                                                   unsigned* __restrict__ Wrb, float* __restrict__ wsreg) {
  __shared__ unsigned Mi[2 * 128 * 64];   // 64 KB packed u16 counts [dir][t][s/2]
  __shared__ float invS[128];
  const int tid = threadIdx.x;
  if (blockIdx.x >= GG) {                 // ---- weight-convert path ----
    int i = (blockIdx.x - GG) * 256 + tid;
    float4 a = *(const float4*)(Wn + (size_t)i * 4);
    float4 b = *(const float4*)(Wo + (size_t)i * 4);
    float4 c = *(const float4*)(Wr + (size_t)i * 4);
    *(uint2*)(Wnb + (size_t)i * 2) = make_uint2(bfpack(a.x, a.y), bfpack(a.z, a.w));
    *(uint2*)(Wob + (size_t)i * 2) = make_uint2(bfpack(b.x, b.y), bfpack(b.z, b.w));
    *(uint2*)(Wrb + (size_t)i * 2) = make_uint2(bfpack(c.x, c.y), bfpack(c.z, c.w));
    float s = fabsf(b.x) + fabsf(b.y) + fabsf(b.z) + fabsf(b.w);
    if (blockIdx.x == GG && tid < 96) {
      float4 d = *(const float4*)(bo + tid * 4);
      s += fabsf(d.x) + fabsf(d.y) + fabsf(d.z) + fabsf(d.w);
    }
#pragma unroll
    for (int mk = 1; mk < 64; mk <<= 1) s += __shfl_xor(s, mk, 64);
    if ((tid & 63) == 0) atomicAdd(wsreg, s);
    return;
  }
  // ---- adjacency path ----
  const int g = blockIdx.x;
  uint4* Mi4 = (uint4*)Mi;
  for (int i = tid; i < 4096; i += 256) Mi4[i] = make_uint4(0, 0, 0, 0);
  __syncthreads();
  const int e0 = g * EPG;
#pragma unroll
  for (int i = 0; i < 8; ++i) {
    int e = e0 + i * 256 + tid;
    int t = tgt[e] & 127;
    int sl = src[e] & 127;
    int dir = (mask[e] != 0) ? 0 : 1;
    atomicAdd(&Mi[dir * 8192 + t * 64 + (sl >> 1)], 1u << ((sl & 1) * 16));
  }
  __syncthreads();
  const int t = tid >> 1, p = tid & 1;
  const int b0 = t * 64 + p * 32;
  unsigned nin = 0, nout = 0;
#pragma unroll 8
  for (int k = 0; k < 32; ++k) { unsigned v = Mi[b0 + ((k + t) & 31)]; nin += (v & 0xffffu) + (v >> 16); }
#pragma unroll 8
  for (int k = 0; k < 32; ++k) { unsigned v = Mi[8192 + b0 + ((k + t) & 31)]; nout += (v & 0xffffu) + (v >> 16); }
  nin += __shfl_xor((int)nin, 1);
  nout += __shfl_xor((int)nout, 1);
  unsigned dg = nin + nout;
  float inv = 1.0f / (float)(dg > 0 ? dg : 1);
  if (p == 0) {
    fin[g * 128 + t] = (float)nin * inv;
    fout[g * 128 + t] = (float)nout * inv;
    invS[t] = inv;
  }
  __syncthreads();
  // coalesced convert+write: 4096 uint4 over [dir][t][w4]  (16 iters x 256 thr)
  uint4* MbQ = (uint4*)(Mb + (size_t)g * 16384);
#pragma unroll
  for (int i = 0; i < 16; ++i) {
    int f = i * 256 + tid;           // uint4 index in [0, 4096)
    int tt = (f >> 4) & 127;         // row within dir
    float iv = invS[tt];
    uint4 v = Mi4[f];
    uint4 o;
    o.x = bfpack((float)(v.x & 0xffffu) * iv, (float)(v.x >> 16) * iv);
    o.y = bfpack((float)(v.y & 0xffffu) * iv, (float)(v.y >> 16) * iv);
    o.z = bfpack((float)(v.z & 0xffffu) * iv, (float)(v.z >> 16) * iv);
    o.w = bfpack((float)(v.w & 0xffffu) * iv, (float)(v.w >> 16) * iv);
    MbQ[f] = o;
  }
}

// ---------------- fused per-graph network, v4: software-pipelined s-chunks ----------------
// grid 256 (1 block/graph), 512 threads (8 waves; wave w owns node rows [16w,16w+16)).
// pre = h*Wr^T + sum_sc [ M~in[:,sc]*(h[sc]*Wn^T) + M~out[:,sc]*(h[sc]*Wo^T) ]
// Double-buffered ys: segment sc computes Y(sc+1) while consuming Y(sc) -> 1 barrier/sc.
__global__ __launch_bounds__(512) void fused_kernel(
    const float* __restrict__ x, const unsigned short* __restrict__ Mb,
    const unsigned short* __restrict__ Wnb, const unsigned short* __restrict__ Wob,
    const unsigned short* __restrict__ Wrb,
    const float* __restrict__ bn, const float* __restrict__ bo,
    const float* __restrict__ fin, const float* __restrict__ fout,
    const float* __restrict__ lng, const float* __restrict__ lnb,
    const float* __restrict__ s,
    const float* __restrict__ flng, const float* __restrict__ flnb,
    const float* __restrict__ linw, const float* __restrict__ bias,
    float* __restrict__ out, float* __restrict__ l1g) {
  __shared__ unsigned short scratch[128 * SSTR];      // 34.8 KB  h [t][f] bf16
  __shared__ unsigned short ys[2][2 * 128 * YSTR];    // 45.1 KB  Y buf [ping][op][c][s_local]
  __shared__ unsigned short sTs[16 * SSTR];           //  4.3 KB  s^T [c][t] bf16
  __shared__ float colsumS[CCd];
  __shared__ float xcs[CCd], axcs[CCd], msk[CCd];

  const int g = blockIdx.x;
  const int tid = threadIdx.x;
  const int wave = tid >> 6;
  const int lane = tid & 63;
  const int m = lane & 15;
  const int q = lane >> 4;
  const unsigned short* Mg = Mb + (size_t)g * 32768;   // [op][t][s]
  unsigned* scratch32 = (unsigned*)scratch;

  // ---- init: x -> scratch [t][f] bf16 ----
  {
    const float4* xg = (const float4*)(x + (size_t)g * 16384);
#pragma unroll
    for (int i = 0; i < 8; ++i) {
      int flat = i * 512 + tid;              // 4096 float4s
      int t = flat >> 5, f = (flat & 31) << 2;
      float4 v = xg[flat];
      int w0 = (t * SSTR + f) >> 1;
      scratch32[w0] = bfpack(v.x, v.y);
      scratch32[w0 + 1] = bfpack(v.z, v.w);
    }
    int t = tid >> 2, c0 = (tid & 3) << 2;
    float4 v = *(const float4*)(s + (size_t)g * 2048 + t * 16 + c0);
    sTs[(c0 + 0) * SSTR + t] = f2bf(v.x);
    sTs[(c0 + 1) * SSTR + t] = f2bf(v.y);
    sTs[(c0 + 2) * SSTR + t] = f2bf(v.z);
    sTs[(c0 + 3) * SSTR + t] = f2bf(v.w);
    if (tid < CCd) {
      float cs = 0.f;
      for (int tt = 0; tt < 128; ++tt) cs += s[(size_t)g * 2048 + tt * 16 + tid];
      colsumS[tid] = cs;
    }
  }
  // per-lane row constants (rows T = 16*wave + q*4 + r), reused across layers
  float fivr[4], fovr[4];
#pragma unroll
  for (int r = 0; r < 4; ++r) {
    fivr[r] = fin[g * 128 + wave * 16 + q * 4 + r];
    fovr[r] = fout[g * 128 + wave * 16 + q * 4 + r];
  }
  // M~ A-fragments cached across ALL layers (layer-invariant): 32 VGPRs
  short8 amf[2][4];
#pragma unroll
  for (int o2 = 0; o2 < 2; ++o2)
#pragma unroll
    for (int sc = 0; sc < 4; ++sc)
      amf[o2][sc] = *(const short8*)(Mg + (size_t)o2 * 16384 + (size_t)(wave * 16 + m) * 128 + sc * 32 + q * 8);
  __syncthreads();

  for (int L = 0; L < LLd; ++L) {
    const unsigned short* WnL = Wnb + (size_t)L * 16384;
    const unsigned short* WoL = Wob + (size_t)L * 16384;
    const unsigned short* WrL = Wrb + (size_t)L * 16384;
    // Y-phase B-frags: W col-slice c = 16*wave + m, all 4 k-chunks, both ops
    short8 wnf[4], wof[4];
#pragma unroll
    for (int ks = 0; ks < 4; ++ks) {
      wnf[ks] = *(const short8*)(WnL + (size_t)(wave * 16 + m) * 128 + ks * 32 + q * 8);
      wof[ks] = *(const short8*)(WoL + (size_t)(wave * 16 + m) * 128 + ks * 32 + q * 8);
    }

    f32x4 pre[8];
#pragma unroll
    for (int ct = 0; ct < 8; ++ct) pre[ct] = (f32x4){0.f, 0.f, 0.f, 0.f};

    // --- R-phase: pre += h * Wr^T (A own rows LDS, B global/L2) ---
#pragma unroll
    for (int ks = 0; ks < 4; ++ks) {
      short8 a = *(const short8*)&scratch[(wave * 16 + m) * SSTR + ks * 32 + q * 8];
#pragma unroll
      for (int ct = 0; ct < 8; ++ct) {
        short8 b = *(const short8*)(WrL + (size_t)(ct * 16 + m) * 128 + ks * 32 + q * 8);
        pre[ct] = MFMA(a, b, pre[ct], 0, 0, 0);
      }
    }

    // --- Y(0) into buf 0 ---
    {
      f32x4 ya[2][2];
#pragma unroll
      for (int o2 = 0; o2 < 2; ++o2)
#pragma unroll
        for (int st = 0; st < 2; ++st) ya[o2][st] = (f32x4){0.f, 0.f, 0.f, 0.f};
#pragma unroll
      for (int ks = 0; ks < 4; ++ks) {
        short8 a0 = *(const short8*)&scratch[(m) * SSTR + ks * 32 + q * 8];
        short8 a1 = *(const short8*)&scratch[(16 + m) * SSTR + ks * 32 + q * 8];
        ya[0][0] = MFMA(a0, wnf[ks], ya[0][0], 0, 0, 0);
        ya[0][1] = MFMA(a1, wnf[ks], ya[0][1], 0, 0, 0);
        ya[1][0] = MFMA(a0, wof[ks], ya[1][0], 0, 0, 0);
        ya[1][1] = MFMA(a1, wof[ks], ya[1][1], 0, 0, 0);
      }
#pragma unroll
      for (int o2 = 0; o2 < 2; ++o2)
#pragma unroll
        for (int st = 0; st < 2; ++st)
#pragma unroll
          for (int r = 0; r < 4; ++r)
            ys[0][o2 * 128 * YSTR + (wave * 16 + m) * YSTR + st * 16 + q * 4 + r] = f2bf(ya[o2][st][r]);
    }
    __syncthreads();

    // --- pipelined s-chunk loop: consume(sc) + produce Y(sc+1) per segment ---
#pragma unroll
    for (int sc = 0; sc < 4; ++sc) {
      f32x4 yb[2][2];
      if (sc < 3) {
#pragma unroll
        for (int o2 = 0; o2 < 2; ++o2)
#pragma unroll
          for (int st = 0; st < 2; ++st) yb[o2][st] = (f32x4){0.f, 0.f, 0.f, 0.f};
#pragma unroll
        for (int ks = 0; ks < 4; ++ks) {
          short8 a0 = *(const short8*)&scratch[((sc + 1) * 32 + m) * SSTR + ks * 32 + q * 8];
          short8 a1 = *(const short8*)&scratch[((sc + 1) * 32 + 16 + m) * SSTR + ks * 32 + q * 8];
          yb[0][0] = MFMA(a0, wnf[ks], yb[0][0], 0, 0, 0);
          yb[0][1] = MFMA(a1, wnf[ks], yb[0][1], 0, 0, 0);
          yb[1][0] = MFMA(a0, wof[ks], yb[1][0], 0, 0, 0);
          yb[1][1] = MFMA(a1, wof[ks], yb[1][1], 0, 0, 0);
        }
      }
      // consume(sc) from buf sc&1
      const unsigned short* bufc = ys[sc & 1];
#pragma unroll
      for (int ct = 0; ct < 8; ++ct) {
        short8 b0 = *(const short8*)&bufc[(ct * 16 + m) * YSTR + q * 8];
        short8 b1 = *(const short8*)&bufc[128 * YSTR + (ct * 16 + m) * YSTR + q * 8];
        pre[ct] = MFMA(amf[0][sc], b0, pre[ct], 0, 0, 0);
        pre[ct] = MFMA(amf[1][sc], b1, pre[ct], 0, 0, 0);
      }
      if (sc < 3) {
        unsigned short* bufp = ys[(sc + 1) & 1];
#pragma unroll
        for (int o2 = 0; o2 < 2; ++o2)
#pragma unroll
          for (int st = 0; st < 2; ++st)
#pragma unroll
            for (int r = 0; r < 4; ++r)
              bufp[o2 * 128 * YSTR + (wave * 16 + m) * YSTR + st * 16 + q * 4 + r] = f2bf(yb[o2][st][r]);
        __syncthreads();
      }
    }

    // --- epilogue: bias mix + LN + ReLU -> scratch rows [16*wave, 16*wave+16) ---
    float bnv[8], bov[8], gv[8], bv[8];
#pragma unroll
    for (int ct = 0; ct < 8; ++ct) {
      int c = L * 128 + ct * 16 + m;
      bnv[ct] = bn[c]; bov[ct] = bo[c]; gv[ct] = lng[c]; bv[ct] = lnb[c];
    }
#pragma unroll
    for (int r = 0; r < 4; ++r) {
      const int tl = q * 4 + r;
      float v[8];
      float sum = 0.f;
#pragma unroll
      for (int ct = 0; ct < 8; ++ct) {
        v[ct] = pre[ct][r] + fivr[r] * bnv[ct] + fovr[r] * bov[ct];
        sum += v[ct];
      }
      sum += __shfl_xor(sum, 1); sum += __shfl_xor(sum, 2);
      sum += __shfl_xor(sum, 4); sum += __shfl_xor(sum, 8);
      const float mu = sum * (1.0f / 128.0f);
      float sq = 0.f;
#pragma unroll
      for (int ct = 0; ct < 8; ++ct) { float d = v[ct] - mu; sq += d * d; }
      sq += __shfl_xor(sq, 1); sq += __shfl_xor(sq, 2);
      sq += __shfl_xor(sq, 4); sq += __shfl_xor(sq, 8);
      const float rstd = rsqrtf(sq * (1.0f / 128.0f) + 1e-5f);
#pragma unroll
      for (int ct = 0; ct < 8; ++ct) {
        float o = fmaxf((v[ct] - mu) * rstd * gv[ct] + bv[ct], 0.0f);
        scratch[(wave * 16 + tl) * SSTR + ct * 16 + m] = f2bf(o);
      }
    }
    __syncthreads();
  }

  // ---- pool: pooled[c][fo] = sum_t s[t][c]*h[t][fo]; wave w owns fo-tile w ----
  float* pooledS = (float*)ys;   // 16 x 132 fp32
  {
    f32x4 pl = (f32x4){0.f, 0.f, 0.f, 0.f};
#pragma unroll
    for (int ks = 0; ks < 4; ++ks) {
      short8 a = *(const short8*)&sTs[m * SSTR + ks * 32 + q * 8];
      short8 b;
#pragma unroll
      for (int j = 0; j < 8; ++j)
        b[j] = (short)scratch[(ks * 32 + q * 8 + j) * SSTR + wave * 16 + m];
      pl = MFMA(a, b, pl, 0, 0, 0);
    }
#pragma unroll
    for (int r = 0; r < 4; ++r) pooledS[(q * 4 + r) * 132 + wave * 16 + m] = pl[r];
  }
  __syncthreads();

  // ---- final LN + lin + mask (threads 0..255) ----
  if (tid < 256) {
    const int c = tid >> 4;
    const int j0 = (tid & 15) << 3;
    float v[8];
#pragma unroll
    for (int jj = 0; jj < 8; ++jj) v[jj] = pooledS[c * 132 + j0 + jj];
    float sum = 0.f;
#pragma unroll
    for (int jj = 0; jj < 8; ++jj) sum += v[jj];
#pragma unroll
    for (int mk = 1; mk < 16; mk <<= 1) sum += __shfl_xor(sum, mk, 64);
    float mu = sum * (1.0f / 128.0f);
    float sq = 0.f;
#pragma unroll
    for (int jj = 0; jj < 8; ++jj) { float d = v[jj] - mu; sq += d * d; }
#pragma unroll
    for (int mk = 1; mk < 16; mk <<= 1) sq += __shfl_xor(sq, mk, 64);
    float rstd = rsqrtf(sq * (1.0f / 128.0f) + 1e-5f);
    float dot = 0.f;
#pragma unroll
    for (int jj = 0; jj < 8; ++jj) {
      float nv = (v[jj] - mu) * rstd * flng[j0 + jj] + flnb[j0 + jj];
      dot += nv * linw[j0 + jj];
    }
#pragma unroll
    for (int mk = 1; mk < 16; mk <<= 1) dot += __shfl_xor(dot, mk, 64);
    if ((tid & 15) == 0) {
      float cm = (colsumS[c] > 0.f) ? 1.0f : 0.0f;
      float xcv = dot * cm;
      out[257 + g * CCd + c] = xcv;
      xcs[c] = xcv; axcs[c] = fabsf(xcv); msk[c] = cm;
    }
  }
  __syncthreads();
  if (tid == 0) {
    float so = 0.f, sa = 0.f, sd = 0.f;
#pragma unroll
    for (int k = 0; k < CCd; ++k) { so += xcs[k]; sa += axcs[k]; sd += msk[k] + 1e-7f; }
    out[g] = so + bias[0];
    l1g[g] = sa / sd;
  }
}

// ---------------- combine: losses = 0.01*reg + 0.01*mean_g(l1g) ----------------
__global__ __launch_bounds__(256) void combine_kernel(const float* __restrict__ l1g, const float* __restrict__ wsreg,
                                                      float* __restrict__ outp) {
  const int tid = threadIdx.x;
  float s2 = l1g[tid];
#pragma unroll
  for (int mk = 1; mk < 64; mk <<= 1) s2 += __shfl_xor(s2, mk, 64);
  __shared__ float rs2[4];
  if ((tid & 63) == 0) rs2[tid >> 6] = s2;
  __syncthreads();
  if (tid == 0) {
    float l1 = (rs2[0] + rs2[1] + rs2[2] + rs2[3]) * (1.0f / GG);
    outp[0] = 0.01f * wsreg[0] + 0.01f * l1;
  }
}

extern "C" void kernel_launch(void* const* d_in, const int* in_sizes, int n_in,
                              void* d_out, int out_size, void* d_ws, size_t ws_size,
                              hipStream_t stream) {
  (void)in_sizes; (void)n_in; (void)out_size; (void)ws_size;
  const float* x    = (const float*)d_in[0];
  const int*   ei   = (const int*)d_in[1];
  const int*   mask = (const int*)d_in[2];
  const float* s    = (const float*)d_in[3];
  const float* Wn   = (const float*)d_in[5];
  const float* bn   = (const float*)d_in[6];
  const float* Wo   = (const float*)d_in[7];
  const float* bo   = (const float*)d_in[8];
  const float* Wr   = (const float*)d_in[9];
  const float* lng  = (const float*)d_in[10];
  const float* lnb  = (const float*)d_in[11];
  const float* flng = (const float*)d_in[12];
  const float* flnb = (const float*)d_in[13];
  const float* linw = (const float*)d_in[14];
  const float* bias = (const float*)d_in[15];
  float* out = (float*)d_out;

  char* ws = (char*)d_ws;
  size_t off = 0;
  auto alloc = [&](size_t b) { char* p = ws + off; off += (b + 255) & ~(size_t)255; return p; };
  unsigned short* Mbuf = (unsigned short*)alloc((size_t)GG * 2 * 128 * 128 * 2);  // 16.8 MB
  float* fin    = (float*)alloc((size_t)NN * 4);
  float* fout   = (float*)alloc((size_t)NN * 4);
  unsigned short* Wnb = (unsigned short*)alloc((size_t)LLd * HD * HD * 2);
  unsigned short* Wob = (unsigned short*)alloc((size_t)LLd * HD * HD * 2);
  unsigned short* Wrb = (unsigned short*)alloc((size_t)LLd * HD * HD * 2);
  float* l1g    = (float*)alloc((size_t)GG * 4);
  float* wsreg  = (float*)alloc(256);

  const int* srcA = ei;
  const int* tgtA = ei + EE;

  hipMemsetAsync(wsreg, 0, 4, stream);
  prep_kernel<<<GG + 48, 256, 0, stream>>>(srcA, tgtA, mask, Wn, Wo, Wr, bo,
      (unsigned*)Mbuf, fin, fout, (unsigned*)Wnb, (unsigned*)Wob, (unsigned*)Wrb, wsreg);
  fused_kernel<<<GG, 512, 0, stream>>>(x, Mbuf, Wnb, Wob, Wrb, bn, bo, fin, fout,
                                       lng, lnb, s, flng, flnb, linw, bias, out, l1g);
  combine_kernel<<<1, 256, 0, stream>>>(l1g, wsreg, out + 256);
}